// Round 6
// baseline (2684.084 us; speedup 1.0000x reference)
//
#include <hip/hip_runtime.h>
#include <hip/hip_fp16.h>

// LSTM forecast: B=256, T_past=512, HID=512, FEAT=1, future=64 -> 576 steps.
// Grid: 128 WGs x 512 threads = 16 batch-groups (bb) x 8 hidden-groups (gb).
// Each WG: 16 batch x 64 hidden, W_hh slice persistent in fp16 MFMA B-frags.
//
// Lessons:
// R1: ordered agent atomics / __threadfence emit buffer_wbl2/inv (whole-L2
//     flush, ~20us/step). All cross-WG traffic relaxed.
// R2 (2380us): latency-bound on serial MALL round trips.
// R3 (2577us): per-step gb0-only decoder dot = straggler; avoid.
// R4 (5091us): per-wave flags = 4x pollers + 4x footprint -> contention.
// R5 (1968us): 8-WG groups, 1 flag store/WG, 1-line poll, deferred atomics.
//     Still ~2.8us/step of waiting: 3-4 serial DEVICE-scope (MALL) RTs.
// R6: XCD-local exchange. Group WGs {bb+16k} share blockIdx%8 -> same XCD
//     under round-robin -> shared L2. Exchange via sc0-ONLY ops (SE scope:
//     bypass L1, terminate in XCD L2, ~250cyc RT vs ~700 MALL). Placement is
//     UNDEFINED per G16 -> runtime token test (sc0 write / agent sync / sc0
//     read; cross-XCD readers see stale 0 -> vote slow); group-wide AND via
//     agent scope so all 8 WGs branch identically. Slow branch == R5 exactly.

#define TPAST 512
#define TTOT  576
#define HIDN  512
#define BW    16            // batch per WG
#define HW    64            // hidden per WG
#define NGRP  8             // WGs per batch group
#define NTHR  512
#define HSTR  520           // hcur LDS row stride (fp16); *2B=1040, 16B-aligned
#define HSTR64 130          // hcur row stride in u64
#define GSTR  261           // gates LDS row stride (fp32)
#define BATCHN 256

typedef _Float16 half8   __attribute__((ext_vector_type(8)));
typedef _Float16 half2v  __attribute__((ext_vector_type(2)));
typedef float    float4v __attribute__((ext_vector_type(4)));

__device__ __forceinline__ float fast_exp(float x) {
    return __builtin_amdgcn_exp2f(x * 1.44269504f);
}
__device__ __forceinline__ float fast_sigmoid(float x) {
    return __builtin_amdgcn_rcpf(1.0f + fast_exp(-x));
}
__device__ __forceinline__ float fast_tanh(float x) {
    return 1.0f - 2.0f * __builtin_amdgcn_rcpf(fast_exp(2.0f * x) + 1.0f);
}

// ---- sc0-only (SE-scope) global ops: bypass L1, terminate in XCD L2 ----
__device__ __forceinline__ void st_sc0(unsigned int* p, unsigned int v) {
    asm volatile("global_store_dword %0, %1, off sc0" :: "v"(p), "v"(v) : "memory");
}
__device__ __forceinline__ unsigned int ld_sc0(const unsigned int* p) {
    unsigned int v;
    asm volatile("global_load_dword %0, %1, off sc0\n\ts_waitcnt vmcnt(0)"
                 : "=v"(v) : "v"(p) : "memory");
    return v;
}
__device__ __forceinline__ void ld4_sc0(const unsigned long long* p,
                                        unsigned long long& a, unsigned long long& b,
                                        unsigned long long& c, unsigned long long& d) {
    asm volatile("global_load_dwordx2 %0, %4, off sc0\n\t"
                 "global_load_dwordx2 %1, %4, off offset:512 sc0\n\t"
                 "global_load_dwordx2 %2, %4, off offset:1024 sc0\n\t"
                 "global_load_dwordx2 %3, %4, off offset:1536 sc0\n\t"
                 "s_waitcnt vmcnt(0)"
                 : "=v"(a), "=v"(b), "=v"(c), "=v"(d) : "v"(p) : "memory");
}
__device__ __forceinline__ void drain_vm() {
    asm volatile("s_waitcnt vmcnt(0)" ::: "memory");
}

__global__ __launch_bounds__(NTHR, 1)
void lstm_forecast_kernel(const float* __restrict__ xseq,
                          const float* __restrict__ Wih,
                          const float* __restrict__ Whh,
                          const float* __restrict__ bih,
                          const float* __restrict__ bhh,
                          const float* __restrict__ Wdec,
                          const float* __restrict__ bdec,
                          float* __restrict__ out,
                          unsigned int* __restrict__ ws32,
                          unsigned int* __restrict__ hbuf)   // fp16 pairs, [2][256][512]
{
    __shared__ _Float16 hcur[BW * HSTR];
    __shared__ float    gates[BW * GSTR];
    __shared__ float    wdecs[HIDN];
    __shared__ float    xcur[BW];
    __shared__ int      vfast_s;

    const int tid  = threadIdx.x;
    const int bb   = blockIdx.x & 15;      // batch group
    const int gb   = blockIdx.x >> 4;      // hidden group 0..7
    const int lane = tid & 63;
    const int wave = tid >> 6;             // 0..7
    const int m    = lane & 15;
    const int q    = lane >> 4;

    unsigned int* gflags  = ws32 + bb * 16;                  // main-loop flags (64B line)
    unsigned int* vflags  = ws32 + 1024 / 4 + bb * 16;       // verification sync (agent)
    unsigned int* okflags = ws32 + 2048 / 4 + bb * 16;       // verdict publish (agent)
    unsigned int* tokens  = ws32 + 3072 / 4;                 // 128 slots x 64B

    // ---- persistent W_hh B-fragments ----
    half8 Wf[2][16];
    {
        #pragma unroll
        for (int cbi = 0; cbi < 2; ++cbi) {
            const int col = (2 * wave + cbi) * 16 + m;        // 0..255
            const int gt  = col >> 6;
            const int jl  = col & 63;
            const float* wr = Whh + (size_t)(gt * HIDN + gb * HW + jl) * HIDN;
            #pragma unroll
            for (int kk = 0; kk < 16; ++kk) {
                const int k0 = kk * 32 + q * 8;
                float4v u = *(const float4v*)(wr + k0);
                float4v v = *(const float4v*)(wr + k0 + 4);
                half8 h;
                h[0] = (_Float16)u[0]; h[1] = (_Float16)u[1];
                h[2] = (_Float16)u[2]; h[3] = (_Float16)u[3];
                h[4] = (_Float16)v[0]; h[5] = (_Float16)v[1];
                h[6] = (_Float16)v[2]; h[7] = (_Float16)v[3];
                Wf[cbi][kk] = h;
            }
        }
    }

    // ---- per-thread elementwise constants ----
    const int eb = tid >> 5;
    const int jj = tid & 31;
    const int j0 = 2 * jj;
    float wih_r[2][4], bsum_r[2][4], wd[2];
    #pragma unroll
    for (int p = 0; p < 2; ++p) {
        const int jg = gb * HW + j0 + p;
        #pragma unroll
        for (int gt = 0; gt < 4; ++gt) {
            const int r = gt * HIDN + jg;
            wih_r[p][gt]  = Wih[r];
            bsum_r[p][gt] = bih[r] + bhh[r];
        }
        wd[p] = Wdec[jg];
    }
    const float bdecv = bdec[0];
    float c0 = 0.01f, c1 = 0.01f;

    // ---- init LDS ----
    {
        const _Float16 hinit = (_Float16)0.01f;
        for (int i = tid; i < BW * HSTR; i += NTHR) hcur[i] = hinit;
        wdecs[tid] = Wdec[tid];
        if (tid < BW) xcur[tid] = xseq[(bb * BW + tid) * TPAST + 0];
    }

    // ---- XCD-placement verification (wave 0): can all 8 group WGs see each
    //      other's sc0 (L2-level) writes? 3 rounds; any miss -> slow path. ----
    if (wave == 0) {
        unsigned int okacc = 1;
        for (int r = 0; r < 3; ++r) {
            if (lane == 0) {
                st_sc0(tokens + (bb * 8 + gb) * 16, (unsigned)(r * 16 + gb + 1));
                drain_vm();
                __hip_atomic_store(vflags + gb, (unsigned)(r + 1),
                                   __ATOMIC_RELAXED, __HIP_MEMORY_SCOPE_AGENT);
            }
            {   // wait until all 8 writers of this round have published (agent)
                int guard = 0;
                for (;;) {
                    unsigned int v = (lane < 8)
                        ? __hip_atomic_load(vflags + lane, __ATOMIC_RELAXED,
                                            __HIP_MEMORY_SCOPE_AGENT)
                        : 0xFFFFFFFFu;
                    if (__ballot(v >= (unsigned)(r + 1)) == ~0ull) break;
                    __builtin_amdgcn_s_sleep(1);
                    if (++guard > (1 << 20)) { okacc = 0; break; }
                }
            }
            unsigned int tv = 0;
            if (lane < 8) tv = ld_sc0(tokens + (bb * 8 + lane) * 16);
            const bool mine = (lane >= 8) || (tv == (unsigned)(r * 16 + lane + 1));
            if (__ballot(mine) != ~0ull) okacc = 0;
        }
        if (lane == 0)
            __hip_atomic_store(okflags + gb, okacc + 1u,
                               __ATOMIC_RELAXED, __HIP_MEMORY_SCOPE_AGENT);
        unsigned int allfast = 0;
        {
            int guard = 0;
            for (;;) {
                unsigned int v = (lane < 8)
                    ? __hip_atomic_load(okflags + lane, __ATOMIC_RELAXED,
                                        __HIP_MEMORY_SCOPE_AGENT)
                    : 1u;
                if (__ballot(v != 0) == ~0ull) {
                    allfast = (__ballot(v == 2u || lane >= 8) == ~0ull) ? 1u : 0u;
                    break;
                }
                __builtin_amdgcn_s_sleep(1);
                if (++guard > (1 << 20)) { allfast = 0; break; }
            }
        }
        if (lane == 0) vfast_s = (int)allfast;
    }
    __syncthreads();
    const bool vfast = (vfast_s != 0);   // identical across the whole group

    const int bglob_e = bb * BW + eb;
    const bool dp_lead = ((lane & 31) == 0);
    float dpv = 0.f;

    for (int t = 0; t < TTOT; ++t) {
        // ---- phase 1: MFMA  gates = h (16x512) * W^T (512x256) ----
        float4v acc0 = {0.f, 0.f, 0.f, 0.f};
        float4v acc1 = {0.f, 0.f, 0.f, 0.f};
        const _Float16* arow = hcur + m * HSTR + q * 8;
        #pragma unroll
        for (int kk = 0; kk < 16; ++kk) {
            half8 af = *(const half8*)(arow + kk * 32);
            acc0 = __builtin_amdgcn_mfma_f32_16x16x32_f16(af, Wf[0][kk], acc0, 0, 0, 0);
            acc1 = __builtin_amdgcn_mfma_f32_16x16x32_f16(af, Wf[1][kk], acc1, 0, 0, 0);
        }
        // ---- phase 2: stage gates to LDS ----
        {
            const int colbase = wave * 32;
            #pragma unroll
            for (int r = 0; r < 4; ++r) {
                gates[(q * 4 + r) * GSTR + colbase +      m] = acc0[r];
                gates[(q * 4 + r) * GSTR + colbase + 16 + m] = acc1[r];
            }
        }
        const int tn = t + 1;
        float xq = 0.f;
        if (tn < TPAST && tid < BW) xq = xseq[(bb * BW + tid) * TPAST + tn];

        __syncthreads();   // barrier A: gates ready; hcur reads complete

        // ---- phase 3: elementwise LSTM + h store ----
        {
            const float xc = xcur[eb];
            const float* grow = gates + eb * GSTR;

            float gi = grow[       j0] + xc * wih_r[0][0] + bsum_r[0][0];
            float gf = grow[ 64  + j0] + xc * wih_r[0][1] + bsum_r[0][1];
            float gg = grow[128  + j0] + xc * wih_r[0][2] + bsum_r[0][2];
            float go = grow[192  + j0] + xc * wih_r[0][3] + bsum_r[0][3];
            c0 = fast_sigmoid(gf) * c0 + fast_sigmoid(gi) * fast_tanh(gg);
            const float h0 = fast_sigmoid(go) * fast_tanh(c0);

            gi = grow[       j0 + 1] + xc * wih_r[1][0] + bsum_r[1][0];
            gf = grow[ 64  + j0 + 1] + xc * wih_r[1][1] + bsum_r[1][1];
            gg = grow[128  + j0 + 1] + xc * wih_r[1][2] + bsum_r[1][2];
            go = grow[192  + j0 + 1] + xc * wih_r[1][3] + bsum_r[1][3];
            c1 = fast_sigmoid(gf) * c1 + fast_sigmoid(gi) * fast_tanh(gg);
            const float h1 = fast_sigmoid(go) * fast_tanh(c1);

            half2v hp; hp[0] = (_Float16)h0; hp[1] = (_Float16)h1;
            const unsigned int bits = __builtin_bit_cast(unsigned int, hp);
            unsigned int* hdst = hbuf
                + (size_t)((tn & 1) * BATCHN + bglob_e) * (HIDN / 2)
                + gb * (HW / 2) + jj;
            if (vfast)
                st_sc0(hdst, bits);
            else
                __hip_atomic_store(hdst, bits, __ATOMIC_RELAXED,
                                   __HIP_MEMORY_SCOPE_AGENT);

            float dp = h0 * wd[0] + h1 * wd[1];
            dp += __shfl_down(dp, 16);
            dp += __shfl_down(dp, 8);
            dp += __shfl_down(dp, 4);
            dp += __shfl_down(dp, 2);
            dp += __shfl_down(dp, 1);
            dpv = dp;   // issued in phase 6, off the critical path
        }

        drain_vm();        // per-wave: h stores at their coherence point
        __syncthreads();   // barrier B: all waves drained

        if (t == TTOT - 1) {
            if (dp_lead)
                atomicAdd(out + bglob_e * TTOT + t,
                          dpv + (gb == 0 ? bdecv : 0.0f));
            break;
        }

        // ---- phase 4: arrive (1 flag store/WG) + poll (1 line, all waves) ----
        const unsigned int target = (unsigned int)tn;
        if (tid == 0) {
            if (vfast) st_sc0(gflags + gb, target);
            else __hip_atomic_store(gflags + gb, target, __ATOMIC_RELAXED,
                                    __HIP_MEMORY_SCOPE_AGENT);
        }
        {
            const unsigned int* slot = gflags + (lane & 7);
            int guard = 0;
            if (vfast) {
                for (;;) {
                    const unsigned int v = ld_sc0(slot);
                    if (__ballot(v >= target) == ~0ull) break;
                    __builtin_amdgcn_s_sleep(1);
                    if (++guard > (1 << 16)) break;   // fail loud, not hung
                }
            } else {
                for (;;) {
                    const unsigned int v = __hip_atomic_load(
                        slot, __ATOMIC_RELAXED, __HIP_MEMORY_SCOPE_AGENT);
                    if (__ballot(v >= target) == ~0ull) break;
                    __builtin_amdgcn_s_sleep(1);
                    if (++guard > (1 << 22)) break;
                }
            }
        }
        __builtin_amdgcn_sched_barrier(0);

        // ---- phase 5: per-wave reload of its 2 rows (2 x 512 fp16) ----
        {
            const int p1 = tn & 1;
            const unsigned long long* hsrc = (const unsigned long long*)hbuf
                + (size_t)(p1 * BATCHN + bb * BW) * (HIDN / 4);
            unsigned long long* hc64 = (unsigned long long*)hcur;
            if (vfast) {
                const unsigned long long* base = hsrc + (2 * wave) * 128 + lane;
                unsigned long long d0, d1, d2, d3;
                ld4_sc0(base, d0, d1, d2, d3);
                hc64[(2 * wave    ) * HSTR64 + lane     ] = d0;
                hc64[(2 * wave    ) * HSTR64 + lane + 64] = d1;
                hc64[(2 * wave + 1) * HSTR64 + lane     ] = d2;
                hc64[(2 * wave + 1) * HSTR64 + lane + 64] = d3;
            } else {
                #pragma unroll
                for (int i = 0; i < 4; ++i) {
                    const int idx = lane + 64 * i;
                    const int row = 2 * wave + (idx >> 7);
                    const int col = idx & 127;
                    hc64[row * HSTR64 + col] =
                        __hip_atomic_load(hsrc + row * (HIDN / 4) + col,
                                          __ATOMIC_RELAXED, __HIP_MEMORY_SCOPE_AGENT);
                }
            }
        }
        __syncthreads();   // barrier C: hcur complete

        // ---- phase 6: deferred out-atomic + next x ----
        if (dp_lead)
            atomicAdd(out + bglob_e * TTOT + t,
                      dpv + (gb == 0 ? bdecv : 0.0f));
        if (tn >= TPAST) {
            const _Float16* hr = hcur + eb * HSTR + jj * 16;
            const float*    wr = wdecs + jj * 16;
            float dx = 0.f;
            #pragma unroll
            for (int u = 0; u < 2; ++u) {
                half8 hv = *(const half8*)(hr + u * 8);
                #pragma unroll
                for (int e = 0; e < 8; ++e)
                    dx += (float)hv[e] * wr[u * 8 + e];
            }
            dx += __shfl_down(dx, 16);
            dx += __shfl_down(dx, 8);
            dx += __shfl_down(dx, 4);
            dx += __shfl_down(dx, 2);
            dx += __shfl_down(dx, 1);
            if (dp_lead) xcur[eb] = dx + bdecv;
        } else {
            if (tid < BW) xcur[tid] = xq;
        }
    }
}

extern "C" void kernel_launch(void* const* d_in, const int* in_sizes, int n_in,
                              void* d_out, int out_size, void* d_ws, size_t ws_size,
                              hipStream_t stream) {
    (void)in_sizes; (void)n_in; (void)ws_size;
    const float* xseq = (const float*)d_in[0];
    // d_in[1] = future_n scalar (fixed 64, shapes hardcoded)
    const float* Wih  = (const float*)d_in[2];
    const float* Whh  = (const float*)d_in[3];
    const float* bih  = (const float*)d_in[4];
    const float* bhh  = (const float*)d_in[5];
    const float* Wdec = (const float*)d_in[6];
    const float* bdec = (const float*)d_in[7];
    float* out = (float*)d_out;

    unsigned int* ws32 = (unsigned int*)d_ws;                  // flags+tokens, 64KB
    unsigned int* hbuf = (unsigned int*)((char*)d_ws + 65536); // [2][256][512] fp16 pairs

    hipMemsetAsync(d_ws, 0, 65536, stream);
    hipMemsetAsync(d_out, 0, (size_t)out_size * sizeof(float), stream);
    lstm_forecast_kernel<<<dim3(128), dim3(NTHR), 0, stream>>>(
        xseq, Wih, Whh, bih, bhh, Wdec, bdec, out, ws32, hbuf);
}

// Round 8
// 2012.946 us; speedup vs baseline: 1.3334x; 1.3334x over previous
//
#include <hip/hip_runtime.h>
#include <hip/hip_fp16.h>
#include <type_traits>

// LSTM forecast: B=256, T_past=512, HID=512, FEAT=1, future=64 -> 576 steps.
// Grid: 128 WGs x 512 threads = 16 groups x 8 WGs. Each WG: 16 batch x 64
// hidden, W_hh slice persistent in fp16 MFMA B-frags.
//
// Lessons:
// R1: ordered agent atomics/__threadfence -> buffer_wbl2/inv (~20us/step).
// R2 (2380us): latency-bound on serial MALL RTs. R3 (2577): gb0 straggler.
// R4 (5091us): per-wave flags -> poller contention.
// R5 (1968us): 8-WG groups, 1 flag/WG, 1-line poll, deferred atomics. BEST.
// R6 (2684us): guessed placement (blockIdx%8) wrong -> fast path never ran;
//     per-step vfast branches alone cost ~700us over R5.
// R7 (FAIL 3.9e-3): discovery engaged fast path but (a) wgxcd publish vs
//     arrive-add unordered (relaxed,relaxed -> observer can read unwritten
//     slot, groupings diverge) and (b) no verification gate: cross-XCD "fast"
//     groups read STALE clean hbuf copies from their own L2 -> ~1-step-stale
//     h drift. Fix: drain between publish and arrive; reinstate 3-round
//     SAME-ADDRESS token test per group (stale-L2-copy detector); clone the
//     main loop (generic lambda) so per-step code is branch-free.

#define TPAST 512
#define TTOT  576
#define HIDN  512
#define BW    16
#define HW    64
#define NGRP  8
#define NWG   128
#define NTHR  512
#define HSTR  520
#define HSTR64 130
#define GSTR  261
#define BATCHN 256

typedef _Float16 half8   __attribute__((ext_vector_type(8)));
typedef _Float16 half2v  __attribute__((ext_vector_type(2)));
typedef float    float4v __attribute__((ext_vector_type(4)));

__device__ __forceinline__ float fast_exp(float x) {
    return __builtin_amdgcn_exp2f(x * 1.44269504f);
}
__device__ __forceinline__ float fast_sigmoid(float x) {
    return __builtin_amdgcn_rcpf(1.0f + fast_exp(-x));
}
__device__ __forceinline__ float fast_tanh(float x) {
    return 1.0f - 2.0f * __builtin_amdgcn_rcpf(fast_exp(2.0f * x) + 1.0f);
}

// ---- sc0-only ops: bypass L1, terminate in the XCD's L2 ----
__device__ __forceinline__ void st_sc0(unsigned int* p, unsigned int v) {
    asm volatile("global_store_dword %0, %1, off sc0" :: "v"(p), "v"(v) : "memory");
}
__device__ __forceinline__ unsigned int ld_sc0(const unsigned int* p) {
    unsigned int v;
    asm volatile("global_load_dword %0, %1, off sc0\n\ts_waitcnt vmcnt(0)"
                 : "=v"(v) : "v"(p) : "memory");
    return v;
}
__device__ __forceinline__ void ld4_sc0(const unsigned long long* p,
                                        unsigned long long& a, unsigned long long& b,
                                        unsigned long long& c, unsigned long long& d) {
    asm volatile("global_load_dwordx2 %0, %4, off sc0\n\t"
                 "global_load_dwordx2 %1, %4, off offset:512 sc0\n\t"
                 "global_load_dwordx2 %2, %4, off offset:1024 sc0\n\t"
                 "global_load_dwordx2 %3, %4, off offset:1536 sc0\n\t"
                 "s_waitcnt vmcnt(0)"
                 : "=v"(a), "=v"(b), "=v"(c), "=v"(d) : "v"(p) : "memory");
}
__device__ __forceinline__ void drain_vm() {
    asm volatile("s_waitcnt vmcnt(0)" ::: "memory");
}

__global__ __launch_bounds__(NTHR, 1)
void lstm_forecast_kernel(const float* __restrict__ xseq,
                          const float* __restrict__ Wih,
                          const float* __restrict__ Whh,
                          const float* __restrict__ bih,
                          const float* __restrict__ bhh,
                          const float* __restrict__ Wdec,
                          const float* __restrict__ bdec,
                          float* __restrict__ out,
                          unsigned int* __restrict__ ws32,
                          unsigned int* __restrict__ hbuf)   // fp16 pairs, [2][256][512]
{
    __shared__ _Float16 hcur[BW * HSTR];
    __shared__ float    gates[BW * GSTR];
    __shared__ float    wdecs[HIDN];
    __shared__ float    xcur[BW];
    __shared__ int      disc_s;
    __shared__ int      vfast_s;

    const int tid  = threadIdx.x;
    const int lane = tid & 63;
    const int wave = tid >> 6;
    const int m    = lane & 15;
    const int q    = lane >> 4;

    unsigned int* flagarea = ws32;                  // 16 groups x 256B
    unsigned int* wgxcd    = ws32 + 4096 / 4;       // 128 u32
    unsigned int* arrive   = ws32 + 4608 / 4;       // 1 u32
    unsigned int* vflags   = ws32 + 5120 / 4;       // 16 groups x 64B
    unsigned int* okflags  = ws32 + 6144 / 4;       // 16 groups x 64B
    unsigned int* tokens   = ws32 + 7168 / 4;       // 16 groups x 8 x 64B

    // ================= topology discovery (race-fixed) =================
    if (tid == 0) {
        unsigned int x;
        asm volatile("s_getreg_b32 %0, hwreg(HW_REG_XCC_ID)" : "=s"(x));
        x &= 7u;
        __hip_atomic_store(wgxcd + blockIdx.x, x + 1u,
                           __ATOMIC_RELAXED, __HIP_MEMORY_SCOPE_AGENT);
        drain_vm();   // R7 fix: publish MUST be at MALL before arrive counts it
        __hip_atomic_fetch_add(arrive, 1u, __ATOMIC_RELAXED,
                               __HIP_MEMORY_SCOPE_AGENT);
        int guard = 0;
        while (__hip_atomic_load(arrive, __ATOMIC_RELAXED,
                                 __HIP_MEMORY_SCOPE_AGENT) < (unsigned)NWG) {
            __builtin_amdgcn_s_sleep(1);
            if (++guard > (1 << 22)) break;   // fail loud, not hung
        }
    }
    __syncthreads();
    unsigned int* dsc = (unsigned int*)gates;       // LDS scratch during discovery
    if (tid < NWG)
        dsc[tid] = __hip_atomic_load(wgxcd + tid, __ATOMIC_RELAXED,
                                     __HIP_MEMORY_SCOPE_AGENT) - 1u;
    __syncthreads();
    if (tid == 0) {
        int n[8] = {0,0,0,0,0,0,0,0};
        int sme = 0, xme = 0;
        const int me = (int)blockIdx.x;
        for (int i = 0; i < NWG; ++i) {
            const int x = (int)(dsc[i] & 7u);
            if (i == me) { sme = n[x]; xme = x; }
            n[x]++;
        }
        int nf = 0, nl = 0, gbx = 0, lbx = 0;
        for (int x = 0; x < 8; ++x) {
            const int fc = n[x] >> 3;
            if (x == xme) { gbx = nf; lbx = nl; }
            nf += fc;
            nl += n[x] - 8 * fc;
        }
        const int fcme = n[xme] >> 3;
        int grp, mem, fst;
        if (sme < 8 * fcme) { grp = gbx + (sme >> 3); mem = sme & 7; fst = 1; }
        else {
            const int lr = lbx + (sme - 8 * fcme);
            grp = nf + (lr >> 3); mem = lr & 7; fst = 0;
        }
        disc_s = (grp << 8) | (mem << 4) | fst;
    }
    __syncthreads();
    const int  bb    = (disc_s >> 8) & 15;
    const int  gb    = (disc_s >> 4) & 7;
    const bool dfast = (disc_s & 1) != 0;

    // ===== 3-round SAME-ADDRESS sc0 token test (R7 fix: the gate is back) ===
    // Cross-XCD member: its L2 caches the round-0 token; rounds 1/2 re-read
    // the stale copy -> mismatch -> vote slow. Same-XCD: always fresh.
    if (wave == 0) {
        int vr = 0;
        if (dfast) {
            unsigned int okacc = 1;
            unsigned int* mytok = tokens + (bb * 8 + gb) * 16;
            for (int r = 0; r < 3; ++r) {
                if (lane == 0) {
                    st_sc0(mytok, (unsigned)(r * 16 + gb + 1));
                    drain_vm();
                    __hip_atomic_store(vflags + bb * 16 + gb, (unsigned)(r + 1),
                                       __ATOMIC_RELAXED, __HIP_MEMORY_SCOPE_AGENT);
                }
                {
                    int guard = 0;
                    for (;;) {
                        unsigned int v = (lane < 8)
                            ? __hip_atomic_load(vflags + bb * 16 + lane,
                                                __ATOMIC_RELAXED,
                                                __HIP_MEMORY_SCOPE_AGENT)
                            : 0xFFFFFFFFu;
                        if (__ballot(v >= (unsigned)(r + 1)) == ~0ull) break;
                        __builtin_amdgcn_s_sleep(1);
                        if (++guard > (1 << 20)) { okacc = 0; break; }
                    }
                }
                unsigned int tv = 0;
                if (lane < 8) tv = ld_sc0(tokens + (bb * 8 + lane) * 16);
                const bool mine = (lane >= 8) || (tv == (unsigned)(r * 16 + lane + 1));
                if (__ballot(mine) != ~0ull) okacc = 0;
            }
            if (lane == 0)
                __hip_atomic_store(okflags + bb * 16 + gb, okacc + 1u,
                                   __ATOMIC_RELAXED, __HIP_MEMORY_SCOPE_AGENT);
            unsigned int allfast = 0;
            {
                int guard = 0;
                for (;;) {
                    unsigned int v = (lane < 8)
                        ? __hip_atomic_load(okflags + bb * 16 + lane,
                                            __ATOMIC_RELAXED,
                                            __HIP_MEMORY_SCOPE_AGENT)
                        : 1u;
                    if (__ballot(v != 0) == ~0ull) {
                        allfast = (__ballot(v == 2u || lane >= 8) == ~0ull) ? 1u : 0u;
                        break;
                    }
                    __builtin_amdgcn_s_sleep(1);
                    if (++guard > (1 << 20)) { allfast = 0; break; }
                }
            }
            vr = (int)allfast;
        }
        if (lane == 0) vfast_s = vr;
    }
    __syncthreads();
    const bool vfast = (vfast_s != 0);

    // ---- persistent W_hh B-fragments ----
    half8 Wf[2][16];
    {
        #pragma unroll
        for (int cbi = 0; cbi < 2; ++cbi) {
            const int col = (2 * wave + cbi) * 16 + m;        // 0..255
            const int gt  = col >> 6;
            const int jl  = col & 63;
            const float* wr = Whh + (size_t)(gt * HIDN + gb * HW + jl) * HIDN;
            #pragma unroll
            for (int kk = 0; kk < 16; ++kk) {
                const int k0 = kk * 32 + q * 8;
                float4v u = *(const float4v*)(wr + k0);
                float4v v = *(const float4v*)(wr + k0 + 4);
                half8 h;
                h[0] = (_Float16)u[0]; h[1] = (_Float16)u[1];
                h[2] = (_Float16)u[2]; h[3] = (_Float16)u[3];
                h[4] = (_Float16)v[0]; h[5] = (_Float16)v[1];
                h[6] = (_Float16)v[2]; h[7] = (_Float16)v[3];
                Wf[cbi][kk] = h;
            }
        }
    }

    // ---- per-thread elementwise constants ----
    const int eb = tid >> 5;
    const int jj = tid & 31;
    const int j0 = 2 * jj;
    float wih_r[2][4], bsum_r[2][4], wd[2];
    #pragma unroll
    for (int p = 0; p < 2; ++p) {
        const int jg = gb * HW + j0 + p;
        #pragma unroll
        for (int gt = 0; gt < 4; ++gt) {
            const int r = gt * HIDN + jg;
            wih_r[p][gt]  = Wih[r];
            bsum_r[p][gt] = bih[r] + bhh[r];
        }
        wd[p] = Wdec[jg];
    }
    const float bdecv = bdec[0];
    float c0 = 0.01f, c1 = 0.01f;

    // ---- init LDS ----
    __syncthreads();   // dsc scratch (gates) free
    {
        const _Float16 hinit = (_Float16)0.01f;
        for (int i = tid; i < BW * HSTR; i += NTHR) hcur[i] = hinit;
        wdecs[tid] = Wdec[tid];
        if (tid < BW) xcur[tid] = xseq[(bb * BW + tid) * TPAST + 0];
    }
    __syncthreads();

    unsigned int* gflags = flagarea + bb * 64;   // 256B line per group
    const int bglob_e = bb * BW + eb;
    const bool dp_lead = ((lane & 31) == 0);
    float dpv = 0.f;

    // ================= main loop, cloned fast/slow (no per-step branches) ===
    auto run = [&](auto FASTC) {
        constexpr bool FAST = decltype(FASTC)::value;
        for (int t = 0; t < TTOT; ++t) {
            // phase 1: MFMA gates = h (16x512) * W^T (512x256)
            float4v acc0 = {0.f, 0.f, 0.f, 0.f};
            float4v acc1 = {0.f, 0.f, 0.f, 0.f};
            const _Float16* arow = hcur + m * HSTR + q * 8;
            #pragma unroll
            for (int kk = 0; kk < 16; ++kk) {
                half8 af = *(const half8*)(arow + kk * 32);
                acc0 = __builtin_amdgcn_mfma_f32_16x16x32_f16(af, Wf[0][kk], acc0, 0, 0, 0);
                acc1 = __builtin_amdgcn_mfma_f32_16x16x32_f16(af, Wf[1][kk], acc1, 0, 0, 0);
            }
            // phase 2: stage gates to LDS
            {
                const int colbase = wave * 32;
                #pragma unroll
                for (int r = 0; r < 4; ++r) {
                    gates[(q * 4 + r) * GSTR + colbase +      m] = acc0[r];
                    gates[(q * 4 + r) * GSTR + colbase + 16 + m] = acc1[r];
                }
            }
            const int tn = t + 1;
            float xq = 0.f;
            if (tn < TPAST && tid < BW) xq = xseq[(bb * BW + tid) * TPAST + tn];

            __syncthreads();   // barrier A

            // phase 3: elementwise LSTM + h store
            {
                const float xc = xcur[eb];
                const float* grow = gates + eb * GSTR;

                float gi = grow[       j0] + xc * wih_r[0][0] + bsum_r[0][0];
                float gf = grow[ 64  + j0] + xc * wih_r[0][1] + bsum_r[0][1];
                float gg = grow[128  + j0] + xc * wih_r[0][2] + bsum_r[0][2];
                float go = grow[192  + j0] + xc * wih_r[0][3] + bsum_r[0][3];
                c0 = fast_sigmoid(gf) * c0 + fast_sigmoid(gi) * fast_tanh(gg);
                const float h0 = fast_sigmoid(go) * fast_tanh(c0);

                gi = grow[       j0 + 1] + xc * wih_r[1][0] + bsum_r[1][0];
                gf = grow[ 64  + j0 + 1] + xc * wih_r[1][1] + bsum_r[1][1];
                gg = grow[128  + j0 + 1] + xc * wih_r[1][2] + bsum_r[1][2];
                go = grow[192  + j0 + 1] + xc * wih_r[1][3] + bsum_r[1][3];
                c1 = fast_sigmoid(gf) * c1 + fast_sigmoid(gi) * fast_tanh(gg);
                const float h1 = fast_sigmoid(go) * fast_tanh(c1);

                half2v hp; hp[0] = (_Float16)h0; hp[1] = (_Float16)h1;
                const unsigned int bits = __builtin_bit_cast(unsigned int, hp);
                unsigned int* hdst = hbuf
                    + (size_t)((tn & 1) * BATCHN + bglob_e) * (HIDN / 2)
                    + gb * (HW / 2) + jj;
                if constexpr (FAST)
                    st_sc0(hdst, bits);                // lands in shared XCD L2
                else
                    __hip_atomic_store(hdst, bits, __ATOMIC_RELAXED,
                                       __HIP_MEMORY_SCOPE_AGENT);

                float dp = h0 * wd[0] + h1 * wd[1];
                dp += __shfl_down(dp, 16);
                dp += __shfl_down(dp, 8);
                dp += __shfl_down(dp, 4);
                dp += __shfl_down(dp, 2);
                dp += __shfl_down(dp, 1);
                dpv = dp;   // issued in phase 6, off the critical path
            }

            drain_vm();        // per-wave: h stores ack'd at coherence point
            __syncthreads();   // barrier B

            if (t == TTOT - 1) {
                if (dp_lead)
                    atomicAdd(out + bglob_e * TTOT + t,
                              dpv + (gb == 0 ? bdecv : 0.0f));
                break;
            }

            // phase 4: arrive + poll
            const unsigned int target = (unsigned int)tn;
            if (tid == 0) {
                if constexpr (FAST) st_sc0(gflags + gb, target);
                else __hip_atomic_store(gflags + gb, target, __ATOMIC_RELAXED,
                                        __HIP_MEMORY_SCOPE_AGENT);
            }
            {
                const unsigned int* slot = gflags + (lane & 7);
                int guard = 0;
                for (;;) {
                    unsigned int v;
                    if constexpr (FAST) v = ld_sc0(slot);
                    else v = __hip_atomic_load(slot, __ATOMIC_RELAXED,
                                               __HIP_MEMORY_SCOPE_AGENT);
                    if (__ballot(v >= target) == ~0ull) break;
                    __builtin_amdgcn_s_sleep(1);
                    if (++guard > (1 << 22)) break;   // fail loud, not hung
                }
            }
            __builtin_amdgcn_sched_barrier(0);

            // phase 5: per-wave reload of its 2 rows (2 x 512 fp16)
            {
                const int p1 = tn & 1;
                const unsigned long long* hsrc = (const unsigned long long*)hbuf
                    + (size_t)(p1 * BATCHN + bb * BW) * (HIDN / 4);
                unsigned long long* hc64 = (unsigned long long*)hcur;
                if constexpr (FAST) {
                    const unsigned long long* base = hsrc + (2 * wave) * 128 + lane;
                    unsigned long long d0, d1, d2, d3;
                    ld4_sc0(base, d0, d1, d2, d3);
                    hc64[(2 * wave    ) * HSTR64 + lane     ] = d0;
                    hc64[(2 * wave    ) * HSTR64 + lane + 64] = d1;
                    hc64[(2 * wave + 1) * HSTR64 + lane     ] = d2;
                    hc64[(2 * wave + 1) * HSTR64 + lane + 64] = d3;
                } else {
                    #pragma unroll
                    for (int i = 0; i < 4; ++i) {
                        const int idx = lane + 64 * i;
                        const int row = 2 * wave + (idx >> 7);
                        const int col = idx & 127;
                        hc64[row * HSTR64 + col] =
                            __hip_atomic_load(hsrc + row * (HIDN / 4) + col,
                                              __ATOMIC_RELAXED,
                                              __HIP_MEMORY_SCOPE_AGENT);
                    }
                }
            }
            __syncthreads();   // barrier C

            // phase 6: deferred out-atomic + next x
            if (dp_lead)
                atomicAdd(out + bglob_e * TTOT + t,
                          dpv + (gb == 0 ? bdecv : 0.0f));
            if (tn >= TPAST) {
                const _Float16* hr = hcur + eb * HSTR + jj * 16;
                const float*    wr = wdecs + jj * 16;
                float dx = 0.f;
                #pragma unroll
                for (int u = 0; u < 2; ++u) {
                    half8 hv = *(const half8*)(hr + u * 8);
                    #pragma unroll
                    for (int e = 0; e < 8; ++e)
                        dx += (float)hv[e] * wr[u * 8 + e];
                }
                dx += __shfl_down(dx, 16);
                dx += __shfl_down(dx, 8);
                dx += __shfl_down(dx, 4);
                dx += __shfl_down(dx, 2);
                dx += __shfl_down(dx, 1);
                if (dp_lead) xcur[eb] = dx + bdecv;
            } else {
                if (tid < BW) xcur[tid] = xq;
            }
        }
    };

    if (vfast) run(std::integral_constant<bool, true>{});
    else       run(std::integral_constant<bool, false>{});
}

extern "C" void kernel_launch(void* const* d_in, const int* in_sizes, int n_in,
                              void* d_out, int out_size, void* d_ws, size_t ws_size,
                              hipStream_t stream) {
    (void)in_sizes; (void)n_in; (void)ws_size;
    const float* xseq = (const float*)d_in[0];
    // d_in[1] = future_n scalar (fixed 64, shapes hardcoded)
    const float* Wih  = (const float*)d_in[2];
    const float* Whh  = (const float*)d_in[3];
    const float* bih  = (const float*)d_in[4];
    const float* bhh  = (const float*)d_in[5];
    const float* Wdec = (const float*)d_in[6];
    const float* bdec = (const float*)d_in[7];
    float* out = (float*)d_out;

    unsigned int* ws32 = (unsigned int*)d_ws;                  // flags+discovery, 16KB
    unsigned int* hbuf = (unsigned int*)((char*)d_ws + 16384); // [2][256][512] fp16 pairs

    hipMemsetAsync(d_ws, 0, 16384, stream);
    hipMemsetAsync(d_out, 0, (size_t)out_size * sizeof(float), stream);
    lstm_forecast_kernel<<<dim3(NWG), dim3(NTHR), 0, stream>>>(
        xseq, Wih, Whh, bih, bhh, Wdec, bdec, out, ws32, hbuf);
}

// Round 9
// 1662.315 us; speedup vs baseline: 1.6147x; 1.2109x over previous
//
#include <hip/hip_runtime.h>
#include <hip/hip_fp16.h>

// LSTM forecast: B=256, T_past=512, HID=512, FEAT=1, future=64 -> 576 steps.
// Grid: 128 WGs x 512 threads = 16 batch-groups (bb) x 8 hidden-groups (gb).
// Each WG: 16 batch x 64 hidden. W_hh slice persistent in fp16 MFMA B-frags.
//
// Lessons:
// R1: ordered agent atomics/__threadfence -> buffer_wbl2/inv (~20us/step).
//     All cross-WG traffic RELAXED agent scope (plain ops to MALL).
// R2 (2380) / R3 (2577) / R4 (5091): 1 poller/WG good; per-step unbalanced
//     work = straggler; per-wave flags = poller contention.
// R5 (1968us): BEST structure. 8-WG groups, 1 flag store/WG, one 32B flag
//     line polled by all waves, deferred atomics, 3 barriers/step.
// R6-R8 (2684/FAIL/2013): XCD-local sc0 exchange is DEAD: gfx950 scope bits
//     are (sc0,sc1)=CU/SE/Agent/System — sc0-only is SHADER-ENGINE scope
//     (8 CUs), not XCD; no XCD-level scope exists. R7's corruption = SE-scope
//     staleness across the XCD; R8's token test correctly vetoed everything.
// R9: clean R5 + zero-atomic out[]: after reload every WG holds full h(t),
//     so out rows 2gb,2gb+1 are computed post-barrier-C as plain stores
//     (balanced, 2 rows/WG). Removes 2048 same-line RMWs/step from the MALL
//     during the sync window and shortens phase 3. Loop uniform over all
//     576 steps (exchange incl. last) so out[575] sees fresh h.

#define TPAST 512
#define TTOT  576
#define HIDN  512
#define BW    16            // batch per WG
#define HW    64            // hidden per WG
#define NGRP  8             // WGs per batch group
#define NWG   128
#define NTHR  512
#define HSTR  520           // hcur LDS row stride (fp16); *2B=1040, 16B-aligned
#define GSTR  261           // gates LDS row stride (fp32)
#define BATCHN 256

typedef _Float16 half8   __attribute__((ext_vector_type(8)));
typedef _Float16 half2v  __attribute__((ext_vector_type(2)));
typedef float    float4v __attribute__((ext_vector_type(4)));
typedef int      int4v   __attribute__((ext_vector_type(4)));

__device__ __forceinline__ float fast_exp(float x) {
    return __builtin_amdgcn_exp2f(x * 1.44269504f);
}
__device__ __forceinline__ float fast_sigmoid(float x) {
    return __builtin_amdgcn_rcpf(1.0f + fast_exp(-x));
}
__device__ __forceinline__ float fast_tanh(float x) {
    return 1.0f - 2.0f * __builtin_amdgcn_rcpf(fast_exp(2.0f * x) + 1.0f);
}

// 32B system-scope load (sc0 sc1): bypasses L1/L2, reads fresh at MALL.
__device__ __forceinline__ void ld32_sys(const void* p, int4v& a, int4v& b) {
    asm volatile("global_load_dwordx4 %0, %2, off sc0 sc1\n\t"
                 "global_load_dwordx4 %1, %2, off offset:16 sc0 sc1\n\t"
                 "s_waitcnt vmcnt(0)"
                 : "=v"(a), "=v"(b) : "v"(p) : "memory");
}
__device__ __forceinline__ void drain_vm() {
    asm volatile("s_waitcnt vmcnt(0)" ::: "memory");
}

__global__ __launch_bounds__(NTHR, 1)
void lstm_forecast_kernel(const float* __restrict__ xseq,
                          const float* __restrict__ Wih,
                          const float* __restrict__ Whh,
                          const float* __restrict__ bih,
                          const float* __restrict__ bhh,
                          const float* __restrict__ Wdec,
                          const float* __restrict__ bdec,
                          float* __restrict__ out,
                          unsigned int* __restrict__ flagbase,
                          unsigned int* __restrict__ hbuf)   // fp16 pairs, [2][256][512]
{
    __shared__ _Float16 hcur[BW * HSTR];   // current h tile, fp16, row=batch
    __shared__ float    gates[BW * GSTR];  // staged MFMA output (16 x 256)
    __shared__ float    wdecs[HIDN];       // W_dec row
    __shared__ float    xcur[BW];

    const int tid  = threadIdx.x;
    const int bb   = blockIdx.x & 15;      // batch group
    const int gb   = blockIdx.x >> 4;      // hidden group 0..7
    const int lane = tid & 63;
    const int wave = tid >> 6;             // 0..7
    const int m    = lane & 15;            // MFMA A-row / D-col
    const int q    = lane >> 4;            // MFMA quad

    // ---- persistent W_hh B-fragments: 2 col-blocks x 16 k-steps (128 VGPRs) ----
    half8 Wf[2][16];
    {
        #pragma unroll
        for (int cbi = 0; cbi < 2; ++cbi) {
            const int col = (2 * wave + cbi) * 16 + m;        // 0..255
            const int gt  = col >> 6;                          // 0=i 1=f 2=g 3=o
            const int jl  = col & 63;
            const float* wr = Whh + (size_t)(gt * HIDN + gb * HW + jl) * HIDN;
            #pragma unroll
            for (int kk = 0; kk < 16; ++kk) {
                const int k0 = kk * 32 + q * 8;
                float4v u = *(const float4v*)(wr + k0);
                float4v v = *(const float4v*)(wr + k0 + 4);
                half8 h;
                h[0] = (_Float16)u[0]; h[1] = (_Float16)u[1];
                h[2] = (_Float16)u[2]; h[3] = (_Float16)u[3];
                h[4] = (_Float16)v[0]; h[5] = (_Float16)v[1];
                h[6] = (_Float16)v[2]; h[7] = (_Float16)v[3];
                Wf[cbi][kk] = h;
            }
        }
    }

    // ---- per-thread elementwise constants: thread -> (batch eb, hidden j0,j0+1)
    const int eb = tid >> 5;               // 0..15 (wave w owns rows 2w,2w+1)
    const int jj = tid & 31;
    const int j0 = 2 * jj;                 // 0..62
    float wih_r[2][4], bsum_r[2][4];
    #pragma unroll
    for (int p = 0; p < 2; ++p) {
        const int jg = gb * HW + j0 + p;
        #pragma unroll
        for (int gt = 0; gt < 4; ++gt) {
            const int r = gt * HIDN + jg;
            wih_r[p][gt]  = Wih[r];
            bsum_r[p][gt] = bih[r] + bhh[r];
        }
    }
    const float bdecv = bdec[0];
    float c0 = 0.01f, c1 = 0.01f;

    // ---- init ----
    {
        const _Float16 hinit = (_Float16)0.01f;
        for (int i = tid; i < BW * HSTR; i += NTHR) hcur[i] = hinit;
        wdecs[tid] = Wdec[tid];            // HIDN == NTHR
        if (tid < BW) xcur[tid] = xseq[(bb * BW + tid) * TPAST + 0];
    }
    __syncthreads();

    unsigned int* gflags = flagbase + bb * 16;   // 64B flag line per group
    const int bglob_e = bb * BW + eb;

    for (int t = 0; t < TTOT; ++t) {
        // ---- phase 1: MFMA  gates_tile = h (16x512) * W^T (512x256) ----
        float4v acc0 = {0.f, 0.f, 0.f, 0.f};
        float4v acc1 = {0.f, 0.f, 0.f, 0.f};
        const _Float16* arow = hcur + m * HSTR + q * 8;
        #pragma unroll
        for (int kk = 0; kk < 16; ++kk) {
            half8 af = *(const half8*)(arow + kk * 32);
            acc0 = __builtin_amdgcn_mfma_f32_16x16x32_f16(af, Wf[0][kk], acc0, 0, 0, 0);
            acc1 = __builtin_amdgcn_mfma_f32_16x16x32_f16(af, Wf[1][kk], acc1, 0, 0, 0);
        }
        // ---- phase 2: stage gates to LDS (C layout: col=m, row=q*4+r) ----
        {
            const int colbase = wave * 32;
            #pragma unroll
            for (int r = 0; r < 4; ++r) {
                gates[(q * 4 + r) * GSTR + colbase +      m] = acc0[r];
                gates[(q * 4 + r) * GSTR + colbase + 16 + m] = acc1[r];
            }
        }
        // prefetch next past-input (latency hides under barrier A + phase 3)
        const int tn = t + 1;
        float xq = 0.f;
        if (tn < TPAST && tid < BW) xq = xseq[(bb * BW + tid) * TPAST + tn];

        __syncthreads();   // barrier A: gates ready; hcur reads complete

        // ---- phase 3: elementwise LSTM + h store (no decoder work here) ----
        {
            const float xc = xcur[eb];
            const float* grow = gates + eb * GSTR;

            float gi = grow[       j0] + xc * wih_r[0][0] + bsum_r[0][0];
            float gf = grow[ 64  + j0] + xc * wih_r[0][1] + bsum_r[0][1];
            float gg = grow[128  + j0] + xc * wih_r[0][2] + bsum_r[0][2];
            float go = grow[192  + j0] + xc * wih_r[0][3] + bsum_r[0][3];
            c0 = fast_sigmoid(gf) * c0 + fast_sigmoid(gi) * fast_tanh(gg);
            const float h0 = fast_sigmoid(go) * fast_tanh(c0);

            gi = grow[       j0 + 1] + xc * wih_r[1][0] + bsum_r[1][0];
            gf = grow[ 64  + j0 + 1] + xc * wih_r[1][1] + bsum_r[1][1];
            gg = grow[128  + j0 + 1] + xc * wih_r[1][2] + bsum_r[1][2];
            go = grow[192  + j0 + 1] + xc * wih_r[1][3] + bsum_r[1][3];
            c1 = fast_sigmoid(gf) * c1 + fast_sigmoid(gi) * fast_tanh(gg);
            const float h1 = fast_sigmoid(go) * fast_tanh(c1);

            half2v hp; hp[0] = (_Float16)h0; hp[1] = (_Float16)h1;
            const unsigned int bits = __builtin_bit_cast(unsigned int, hp);
            unsigned int* hdst = hbuf
                + (size_t)((tn & 1) * BATCHN + bglob_e) * (HIDN / 2)
                + gb * (HW / 2) + jj;
            __hip_atomic_store(hdst, bits, __ATOMIC_RELAXED,
                               __HIP_MEMORY_SCOPE_AGENT);
        }

        drain_vm();        // per-wave: h stores ack'd at MALL
        __syncthreads();   // barrier B: all waves drained

        // ---- phase 4: arrive (1 flag store/WG) + poll (1 line, all waves) ----
        const unsigned int target = (unsigned int)tn;
        if (tid == 0)
            __hip_atomic_store(gflags + gb, target, __ATOMIC_RELAXED,
                               __HIP_MEMORY_SCOPE_AGENT);
        {
            const unsigned int* slot = gflags + (lane & 7);   // 32B, one line
            int guard = 0;
            for (;;) {
                const unsigned int v = __hip_atomic_load(
                    slot, __ATOMIC_RELAXED, __HIP_MEMORY_SCOPE_AGENT);
                if (__ballot(v >= target) == ~0ull) break;
                __builtin_amdgcn_s_sleep(1);
                if (++guard > (1 << 22)) break;   // fail loud, not hung
            }
        }
        __builtin_amdgcn_sched_barrier(0);   // keep reload below the spin

        // ---- phase 5: per-wave reload of its 2 rows (2 x 512 fp16) ----
        {
            const int p1 = tn & 1;
            const char* hsrc = (const char*)hbuf
                + ((size_t)(p1 * BATCHN + bb * BW)) * (HIDN * 2);
            const int row = 2 * wave + (lane >> 5);      // 0..15
            const int cb  = (lane & 31) * 32;            // byte offset in row
            int4v a, b;
            ld32_sys(hsrc + row * (HIDN * 2) + cb, a, b);
            _Float16* dst = hcur + row * HSTR + (lane & 31) * 16;
            *(int4v*)(dst)     = a;
            *(int4v*)(dst + 8) = b;
        }
        __syncthreads();   // barrier C: full h(t) tile in hcur

        // ---- phase 6: decoder from the full fresh tile ----
        // out rows 2gb,2gb+1 by waves 0,1 (balanced: 2 rows/WG, plain stores)
        if (wave < 2) {
            const int brow = 2 * gb + wave;              // 0..15
            const _Float16* hr = hcur + brow * HSTR + lane * 8;
            const float*    wr = wdecs + lane * 8;
            half8 hv = *(const half8*)hr;
            float dx = 0.f;
            #pragma unroll
            for (int e = 0; e < 8; ++e) dx += (float)hv[e] * wr[e];
            dx += __shfl_down(dx, 32);
            dx += __shfl_down(dx, 16);
            dx += __shfl_down(dx, 8);
            dx += __shfl_down(dx, 4);
            dx += __shfl_down(dx, 2);
            dx += __shfl_down(dx, 1);
            if (lane == 0)
                out[(bb * BW + brow) * TTOT + t] = dx + bdecv;
        }
        // future x_{t+1} for all 16 rows (wave w covers its own rows 2w,2w+1)
        if (tn >= TPAST) {
            const _Float16* hr = hcur + eb * HSTR + jj * 16;
            const float*    wr = wdecs + jj * 16;
            float dx = 0.f;
            #pragma unroll
            for (int u = 0; u < 2; ++u) {
                half8 hv = *(const half8*)(hr + u * 8);
                #pragma unroll
                for (int e = 0; e < 8; ++e)
                    dx += (float)hv[e] * wr[u * 8 + e];
            }
            dx += __shfl_down(dx, 16);
            dx += __shfl_down(dx, 8);
            dx += __shfl_down(dx, 4);
            dx += __shfl_down(dx, 2);
            dx += __shfl_down(dx, 1);
            if ((lane & 31) == 0) xcur[eb] = dx + bdecv;  // own-wave write/read
        } else {
            if (tid < BW) xcur[tid] = xq;  // cross-wave reads ordered by barrier A
        }
    }
}

extern "C" void kernel_launch(void* const* d_in, const int* in_sizes, int n_in,
                              void* d_out, int out_size, void* d_ws, size_t ws_size,
                              hipStream_t stream) {
    (void)in_sizes; (void)n_in; (void)ws_size; (void)out_size;
    const float* xseq = (const float*)d_in[0];
    // d_in[1] = future_n scalar (fixed 64, shapes hardcoded)
    const float* Wih  = (const float*)d_in[2];
    const float* Whh  = (const float*)d_in[3];
    const float* bih  = (const float*)d_in[4];
    const float* bhh  = (const float*)d_in[5];
    const float* Wdec = (const float*)d_in[6];
    const float* bdec = (const float*)d_in[7];
    float* out = (float*)d_out;

    unsigned int* flags = (unsigned int*)d_ws;                // 16 groups x 64B
    unsigned int* hbuf  = (unsigned int*)((char*)d_ws + 8192);// [2][256][512] fp16 pairs

    hipMemsetAsync(d_ws, 0, 8192, stream);
    // no d_out memset needed: every (b,t) gets exactly one plain store
    lstm_forecast_kernel<<<dim3(NWG), dim3(NTHR), 0, stream>>>(
        xseq, Wih, Whh, bih, bhh, Wdec, bdec, out, flags, hbuf);
}